// Round 2
// baseline (327.017 us; speedup 1.0000x reference)
//
#include <hip/hip_runtime.h>

#define BATCH 2
#define SEQ   4096
#define HID   256
#define NHEAD 8
#define DH    32
#define RESCALE_THR 8.0f

typedef __attribute__((ext_vector_type(8))) _Float16 half8;
typedef __attribute__((ext_vector_type(4))) _Float16 half4;
typedef __attribute__((ext_vector_type(4))) float    f32x4;

// ---------------------------------------------------------------- convert
__global__ void cvt_f32_f16(const float* __restrict__ src,
                            _Float16* __restrict__ dst, int n) {
    int i = (blockIdx.x * blockDim.x + threadIdx.x) * 4;
    if (i >= n) return;
    f32x4 v = *reinterpret_cast<const f32x4*>(src + i);
    half4 h;
#pragma unroll
    for (int c = 0; c < 4; ++c) h[c] = (_Float16)v[c];
    *reinterpret_cast<half4*>(dst + i) = h;
}

// all 4 weight matrices in one launch; blockIdx.y selects the source
__global__ void cvt_w4(const float* __restrict__ a, const float* __restrict__ b,
                       const float* __restrict__ c, const float* __restrict__ d,
                       _Float16* __restrict__ dst) {
    const float* srcs[4] = {a, b, c, d};
    const float* s = srcs[blockIdx.y];
    const int i = (blockIdx.x * blockDim.x + threadIdx.x) * 4;
    f32x4 v = *reinterpret_cast<const f32x4*>(s + i);
    half4 h;
#pragma unroll
    for (int k = 0; k < 4; ++k) h[k] = (_Float16)v[k];
    *reinterpret_cast<half4*>(dst + (size_t)blockIdx.y * HID * HID + i) = h;
}

// ---------------------------------------------------------------- QKV proj
__global__ __launch_bounds__(256) void qkv_proj(
    const _Float16* __restrict__ xh, const _Float16* __restrict__ Wh,
    const float* __restrict__ bq, const float* __restrict__ bk,
    const float* __restrict__ bv,
    _Float16* __restrict__ Qh, _Float16* __restrict__ Kh,
    _Float16* __restrict__ Vt)
{
    const int z   = blockIdx.z;
    const int m0  = blockIdx.x * 64;
    const int n0  = blockIdx.y * 64;
    const int tid = threadIdx.x;
    const int w   = tid >> 6, lane = tid & 63;
    const int lr  = lane & 15, lg = lane >> 4;
    const int wr  = (w >> 1) * 32, wc = (w & 1) * 32;

    const _Float16* Wp = Wh + (size_t)z * HID * HID;
    const float* bias = (z == 0) ? bq : (z == 1) ? bk : bv;

    f32x4 acc[2][2] = {};
    const int ar = m0 + wr + lr;
    const int br = n0 + wc + lr;
#pragma unroll
    for (int ks = 0; ks < 8; ++ks) {
        const int ko = ks * 32 + lg * 8;
        half8 a0 = *reinterpret_cast<const half8*>(xh + (size_t)ar * HID + ko);
        half8 a1 = *reinterpret_cast<const half8*>(xh + (size_t)(ar + 16) * HID + ko);
        half8 b0 = *reinterpret_cast<const half8*>(Wp + (size_t)br * HID + ko);
        half8 b1 = *reinterpret_cast<const half8*>(Wp + (size_t)(br + 16) * HID + ko);
        acc[0][0] = __builtin_amdgcn_mfma_f32_16x16x32_f16(a0, b0, acc[0][0], 0, 0, 0);
        acc[0][1] = __builtin_amdgcn_mfma_f32_16x16x32_f16(a0, b1, acc[0][1], 0, 0, 0);
        acc[1][0] = __builtin_amdgcn_mfma_f32_16x16x32_f16(a1, b0, acc[1][0], 0, 0, 0);
        acc[1][1] = __builtin_amdgcn_mfma_f32_16x16x32_f16(a1, b1, acc[1][1], 0, 0, 0);
    }
#pragma unroll
    for (int mf = 0; mf < 2; ++mf)
#pragma unroll
    for (int nf = 0; nf < 2; ++nf)
#pragma unroll
    for (int r = 0; r < 4; ++r) {
        const int m  = m0 + wr + mf * 16 + lg * 4 + r;
        const int o  = n0 + wc + nf * 16 + lr;
        const int bb = m >> 12, nn = m & (SEQ - 1);
        const int hh = o >> 5,  dd = o & (DH - 1);
        float v = acc[mf][nf][r] + bias[o];
        if (z == 0) {
            Qh[(((size_t)(bb * NHEAD + hh) * SEQ) + nn) * DH + dd] =
                (_Float16)(v * 0.17677669529663687f);
        } else if (z == 1) {
            Kh[(((size_t)(bb * NHEAD + hh) * SEQ) + nn) * DH + dd] = (_Float16)v;
        } else {
            Vt[(((size_t)(bb * NHEAD + hh) * DH) + dd) * SEQ + nn] = (_Float16)v;
        }
    }
}

// ---------------------------------------------------------------- attention
// grid (SEQ/32, BATCH), 1024 threads = 16 waves.
// wave w: head = w&7, key-half = w>>3 (j-split x2 for occupancy).
// Chunked staging: 128 keys per barrier triple. Defer-max online softmax
// (THR=8): no shuffle reductions on the common path. In-block merge of the
// two key-halves at the end via LDS.
__global__ __launch_bounds__(1024, 4) void attn_kernel(
    const _Float16* __restrict__ Qh, const _Float16* __restrict__ Kh,
    const _Float16* __restrict__ Vt, const float* __restrict__ pos,
    _Float16* __restrict__ AO)
{
    __shared__ __align__(16) float pi[32][4];
    __shared__ __align__(16) float pj[2][128][4];
    __shared__ __align__(16) float bias_t[2][128][33];   // [half][col][row], padded
    __shared__ __align__(16) _Float16 Pl[16][2048];      // 4KB per wave, XOR-swizzled

    const int b    = blockIdx.y;
    const int i0   = blockIdx.x * 32;
    const int tid  = threadIdx.x;
    const int w    = tid >> 6;
    const int hh   = w & 7;          // head
    const int jh   = w >> 3;         // key-half
    const int lane = tid & 63;
    const int lr   = lane & 15, lg = lane >> 4;

    if (tid < 32) {
        const float* p = pos + (size_t)(b * SEQ + i0 + tid) * 3;
        float x = p[0], y = p[1], z = p[2];
        pi[tid][0] = x; pi[tid][1] = y; pi[tid][2] = z;
        pi[tid][3] = x * x + y * y + z * z;
    }

    const size_t bhh = (size_t)(b * NHEAD + hh);
    const _Float16* Qbase = Qh + (bhh * SEQ + i0) * DH;
    const _Float16* Kbase = Kh + bhh * SEQ * DH;
    const _Float16* Vbase = Vt + bhh * DH * SEQ;
    const int jbase = jh * (SEQ / 2);

    const half8 aq0 = *reinterpret_cast<const half8*>(Qbase + (size_t)lr * DH + lg * 8);
    const half8 aq1 = *reinterpret_cast<const half8*>(Qbase + (size_t)(16 + lr) * DH + lg * 8);

    f32x4 acc[2][2] = {};
    float mrun[2][4], lsum[2][4];
#pragma unroll
    for (int mf = 0; mf < 2; ++mf)
#pragma unroll
    for (int r = 0; r < 4; ++r) { mrun[mf][r] = -__builtin_inff(); lsum[mf][r] = 0.f; }

    char* Pbytes = (char*)&Pl[w][0];

    for (int ch = 0; ch < 16; ++ch) {
        const int c0 = ch * 128;
        __syncthreads();                        // bias_t/pj reuse from prev chunk
        if (tid < 256) {
            const int hf = tid >> 7, jc = tid & 127;
            const float* p = pos + (size_t)(b * SEQ + hf * (SEQ / 2) + c0 + jc) * 3;
            float x = p[0], y = p[1], z = p[2];
            pj[hf][jc][0] = x; pj[hf][jc][1] = y; pj[hf][jc][2] = z;
            pj[hf][jc][3] = x * x + y * y + z * z;
        }
        __syncthreads();
        {   // bias tile for both halves: [2][128] cols x 32 rows, 8 vals/thread
            const int hf  = tid >> 9;
            const int col = (tid >> 2) & 127;
            const int r0  = (tid & 3) * 8;
            const float xj = pj[hf][col][0], yj = pj[hf][col][1];
            const float zj = pj[hf][col][2], sj = pj[hf][col][3];
#pragma unroll
            for (int r = 0; r < 8; ++r) {
                const int row = r0 + r;
                float dot = pi[row][0] * xj + pi[row][1] * yj + pi[row][2] * zj;
                float d2  = pi[row][3] + sj - 2.f * dot;
                bias_t[hf][col][row] = -0.1f * sqrtf(fmaxf(d2, 0.f));
            }
        }
        __syncthreads();

#pragma unroll
        for (int sub = 0; sub < 2; ++sub) {
            const int jc0 = sub * 64;
            const int j0  = jbase + c0 + jc0;

            half8 bk8[4];
#pragma unroll
            for (int cf = 0; cf < 4; ++cf)
                bk8[cf] = *reinterpret_cast<const half8*>(
                    Kbase + (size_t)(j0 + cf * 16 + lr) * DH + lg * 8);

#pragma unroll
            for (int mf = 0; mf < 2; ++mf) {
                float vv[4][4];
#pragma unroll
                for (int cf = 0; cf < 4; ++cf) {
                    f32x4 zero = {};
                    f32x4 sv = __builtin_amdgcn_mfma_f32_16x16x32_f16(
                        mf ? aq1 : aq0, bk8[cf], zero, 0, 0, 0);
                    f32x4 bb = *reinterpret_cast<const f32x4*>(
                        &bias_t[jh][jc0 + cf * 16 + lr][mf * 16 + lg * 4]);
#pragma unroll
                    for (int r = 0; r < 4; ++r) vv[cf][r] = sv[r] + bb[r];
                }
                float tmax4[4];
                int allok = 1;
#pragma unroll
                for (int r = 0; r < 4; ++r) {
                    tmax4[r] = fmaxf(fmaxf(vv[0][r], vv[1][r]), fmaxf(vv[2][r], vv[3][r]));
                    allok &= (tmax4[r] <= mrun[mf][r] + RESCALE_THR) ? 1 : 0;
                }
                if (!__all(allok)) {            // rare: true max update + rescale
#pragma unroll
                    for (int r = 0; r < 4; ++r) {
                        float tm = tmax4[r];
#pragma unroll
                        for (int msk = 8; msk >= 1; msk >>= 1)
                            tm = fmaxf(tm, __shfl_xor(tm, msk, 64));
                        const float mnew  = fmaxf(mrun[mf][r], tm);
                        const float alpha = __expf(mrun[mf][r] - mnew);
                        lsum[mf][r] *= alpha;
                        acc[mf][0][r] *= alpha;
                        acc[mf][1][r] *= alpha;
                        mrun[mf][r] = mnew;
                    }
                }
#pragma unroll
                for (int cf = 0; cf < 4; ++cf) {
                    const int colb = (cf * 16 + lr) * 2;
#pragma unroll
                    for (int r = 0; r < 4; ++r) {
                        const int row = mf * 16 + lg * 4 + r;
                        const float p = __expf(vv[cf][r] - mrun[mf][r]);
                        lsum[mf][r] += p;       // lane-local partial sum
                        const int off = (row * 128 + colb) ^ ((row & 7) << 4);
                        *reinterpret_cast<_Float16*>(Pbytes + off) = (_Float16)p;
                    }
                }
            }

            // PV: acc += P(32x64) @ V(64x32); wave-private P, no barrier
#pragma unroll
            for (int ks = 0; ks < 2; ++ks) {
                half8 bv0 = *reinterpret_cast<const half8*>(
                    Vbase + (size_t)lr * SEQ + j0 + ks * 32 + lg * 8);
                half8 bv1 = *reinterpret_cast<const half8*>(
                    Vbase + (size_t)(16 + lr) * SEQ + j0 + ks * 32 + lg * 8);
#pragma unroll
                for (int mf = 0; mf < 2; ++mf) {
                    const int prow = mf * 16 + lr;
                    const int poff = (prow * 128 + (ks * 32 + lg * 8) * 2) ^ ((prow & 7) << 4);
                    half8 pa = *reinterpret_cast<const half8*>(Pbytes + poff);
                    acc[mf][0] = __builtin_amdgcn_mfma_f32_16x16x32_f16(pa, bv0, acc[mf][0], 0, 0, 0);
                    acc[mf][1] = __builtin_amdgcn_mfma_f32_16x16x32_f16(pa, bv1, acc[mf][1], 0, 0, 0);
                }
            }
        }
    }

    // ---- final: reduce lane-local sums once, then merge the two key-halves
#pragma unroll
    for (int mf = 0; mf < 2; ++mf)
#pragma unroll
    for (int r = 0; r < 4; ++r) {
        float s = lsum[mf][r];
#pragma unroll
        for (int msk = 8; msk >= 1; msk >>= 1) s += __shfl_xor(s, msk, 64);
        lsum[mf][r] = s;
    }
    __syncthreads();
    float* accL = reinterpret_cast<float*>(&Pl[0][0]);        // [16][32][32]
    float* mlL  = reinterpret_cast<float*>(&bias_t[0][0][0]); // [16][32][2]
#pragma unroll
    for (int mf = 0; mf < 2; ++mf)
#pragma unroll
    for (int r = 0; r < 4; ++r) {
        const int row = mf * 16 + lg * 4 + r;
#pragma unroll
        for (int df = 0; df < 2; ++df)
            accL[(w * 32 + row) * 32 + df * 16 + lr] = acc[mf][df][r];
        if (lr == 0) {
            mlL[(w * 32 + row) * 2 + 0] = mrun[mf][r];
            mlL[(w * 32 + row) * 2 + 1] = lsum[mf][r];
        }
    }
    __syncthreads();
    if (w < 8) {
#pragma unroll
        for (int mf = 0; mf < 2; ++mf)
#pragma unroll
        for (int r = 0; r < 4; ++r) {
            const int row = mf * 16 + lg * 4 + r;
            const float m0 = mlL[(w * 32 + row) * 2],       l0 = mlL[(w * 32 + row) * 2 + 1];
            const float m1 = mlL[((w + 8) * 32 + row) * 2], l1 = mlL[((w + 8) * 32 + row) * 2 + 1];
            const float mm = fmaxf(m0, m1);
            const float e0 = __expf(m0 - mm), e1 = __expf(m1 - mm);
            const float inv = 1.f / (l0 * e0 + l1 * e1);
#pragma unroll
            for (int df = 0; df < 2; ++df) {
                const float o = (accL[(w * 32 + row) * 32 + df * 16 + lr] * e0 +
                                 accL[((w + 8) * 32 + row) * 32 + df * 16 + lr] * e1) * inv;
                AO[((size_t)(b * SEQ + i0 + row)) * HID + hh * DH + df * 16 + lr] = (_Float16)o;
            }
        }
    }
}

// ---------------------------------------------------------------- out proj
__global__ __launch_bounds__(256) void out_proj(
    const _Float16* __restrict__ AO, const _Float16* __restrict__ Woh,
    const float* __restrict__ bo, float* __restrict__ out)
{
    const int m0  = blockIdx.x * 64;
    const int n0  = blockIdx.y * 64;
    const int tid = threadIdx.x;
    const int w   = tid >> 6, lane = tid & 63;
    const int lr  = lane & 15, lg = lane >> 4;
    const int wr  = (w >> 1) * 32, wc = (w & 1) * 32;

    f32x4 acc[2][2] = {};
    const int ar = m0 + wr + lr;
    const int br = n0 + wc + lr;
#pragma unroll
    for (int ks = 0; ks < 8; ++ks) {
        const int ko = ks * 32 + lg * 8;
        half8 a0 = *reinterpret_cast<const half8*>(AO + (size_t)ar * HID + ko);
        half8 a1 = *reinterpret_cast<const half8*>(AO + (size_t)(ar + 16) * HID + ko);
        half8 b0 = *reinterpret_cast<const half8*>(Woh + (size_t)br * HID + ko);
        half8 b1 = *reinterpret_cast<const half8*>(Woh + (size_t)(br + 16) * HID + ko);
        acc[0][0] = __builtin_amdgcn_mfma_f32_16x16x32_f16(a0, b0, acc[0][0], 0, 0, 0);
        acc[0][1] = __builtin_amdgcn_mfma_f32_16x16x32_f16(a0, b1, acc[0][1], 0, 0, 0);
        acc[1][0] = __builtin_amdgcn_mfma_f32_16x16x32_f16(a1, b0, acc[1][0], 0, 0, 0);
        acc[1][1] = __builtin_amdgcn_mfma_f32_16x16x32_f16(a1, b1, acc[1][1], 0, 0, 0);
    }
#pragma unroll
    for (int mf = 0; mf < 2; ++mf)
#pragma unroll
    for (int nf = 0; nf < 2; ++nf)
#pragma unroll
    for (int r = 0; r < 4; ++r) {
        const int m = m0 + wr + mf * 16 + lg * 4 + r;
        const int o = n0 + wc + nf * 16 + lr;
        out[(size_t)m * HID + o] = acc[mf][nf][r] + bo[o];
    }
}

// ---------------------------------------------------------------- launch
extern "C" void kernel_launch(void* const* d_in, const int* in_sizes, int n_in,
                              void* d_out, int out_size, void* d_ws, size_t ws_size,
                              hipStream_t stream)
{
    const float* x   = (const float*)d_in[0];
    const float* pos = (const float*)d_in[1];
    const float* Wq  = (const float*)d_in[2];
    const float* bq  = (const float*)d_in[3];
    const float* Wk  = (const float*)d_in[4];
    const float* bk  = (const float*)d_in[5];
    const float* Wv  = (const float*)d_in[6];
    const float* bv  = (const float*)d_in[7];
    const float* Wo  = (const float*)d_in[8];
    const float* bo  = (const float*)d_in[9];
    float* out = (float*)d_out;

    char* ws = (char*)d_ws;
    _Float16* Qh = (_Float16*)(ws);                 // 4 MB
    _Float16* Kh = (_Float16*)(ws + (4  << 20));    // 4 MB
    _Float16* Vt = (_Float16*)(ws + (8  << 20));    // 4 MB
    _Float16* xh = (_Float16*)(ws + (12 << 20));    // 4 MB (reused as AO)
    _Float16* AO = xh;                              // safe: attn runs after qkv_proj
    _Float16* Wh = (_Float16*)(ws + (16 << 20));    // 512 KB

    const int NX = BATCH * SEQ * HID;               // 2,097,152
    const int NW = HID * HID;                       // 65,536
    cvt_f32_f16<<<NX / 1024, 256, 0, stream>>>(x, xh, NX);
    cvt_w4<<<dim3(NW / 1024, 4), 256, 0, stream>>>(Wq, Wk, Wv, Wo, Wh);

    qkv_proj<<<dim3(BATCH * SEQ / 64, HID / 64, 3), 256, 0, stream>>>(
        xh, Wh, bq, bk, bv, Qh, Kh, Vt);

    attn_kernel<<<dim3(SEQ / 32, BATCH), 1024, 0, stream>>>(Qh, Kh, Vt, pos, AO);

    out_proj<<<dim3(BATCH * SEQ / 64, HID / 64), 256, 0, stream>>>(
        AO, Wh + 3 * NW, bo, out);
}

// Round 3
// 235.744 us; speedup vs baseline: 1.3872x; 1.3872x over previous
//
#include <hip/hip_runtime.h>

#define BATCH 2
#define SEQ   4096
#define HID   256
#define NHEAD 8
#define DH    32
// defer-max threshold in log2 units (≈ 8 nats)
#define THR_L2 11.5f
// 1/sqrt(32) * log2(e)
#define QSCALE 0.25501639769925074f
// -(1/10) * log2(e)
#define BIASC (-0.14426950408889634f)

typedef __attribute__((ext_vector_type(8))) _Float16 half8;
typedef __attribute__((ext_vector_type(4))) _Float16 half4;
typedef __attribute__((ext_vector_type(4))) float    f32x4;

// ---------------------------------------------------------------- convert
__global__ void cvt_f32_f16(const float* __restrict__ src,
                            _Float16* __restrict__ dst, int n) {
    int i = (blockIdx.x * blockDim.x + threadIdx.x) * 4;
    if (i >= n) return;
    f32x4 v = *reinterpret_cast<const f32x4*>(src + i);
    half4 h;
#pragma unroll
    for (int c = 0; c < 4; ++c) h[c] = (_Float16)v[c];
    *reinterpret_cast<half4*>(dst + i) = h;
}

__global__ void cvt_w4(const float* __restrict__ a, const float* __restrict__ b,
                       const float* __restrict__ c, const float* __restrict__ d,
                       _Float16* __restrict__ dst) {
    const float* srcs[4] = {a, b, c, d};
    const float* s = srcs[blockIdx.y];
    const int i = (blockIdx.x * blockDim.x + threadIdx.x) * 4;
    f32x4 v = *reinterpret_cast<const f32x4*>(s + i);
    half4 h;
#pragma unroll
    for (int k = 0; k < 4; ++k) h[k] = (_Float16)v[k];
    *reinterpret_cast<half4*>(dst + (size_t)blockIdx.y * HID * HID + i) = h;
}

// ---------------------------------------------------------------- QKV proj
__global__ __launch_bounds__(256) void qkv_proj(
    const _Float16* __restrict__ xh, const _Float16* __restrict__ Wh,
    const float* __restrict__ bq, const float* __restrict__ bk,
    const float* __restrict__ bv,
    _Float16* __restrict__ Qh, _Float16* __restrict__ Kh,
    _Float16* __restrict__ Vt)
{
    const int z   = blockIdx.z;
    const int m0  = blockIdx.x * 64;
    const int n0  = blockIdx.y * 64;
    const int tid = threadIdx.x;
    const int w   = tid >> 6, lane = tid & 63;
    const int lr  = lane & 15, lg = lane >> 4;
    const int wr  = (w >> 1) * 32, wc = (w & 1) * 32;

    const _Float16* Wp = Wh + (size_t)z * HID * HID;
    const float* bias = (z == 0) ? bq : (z == 1) ? bk : bv;

    f32x4 acc[2][2] = {};
    const int ar = m0 + wr + lr;
    const int br = n0 + wc + lr;
#pragma unroll
    for (int ks = 0; ks < 8; ++ks) {
        const int ko = ks * 32 + lg * 8;
        half8 a0 = *reinterpret_cast<const half8*>(xh + (size_t)ar * HID + ko);
        half8 a1 = *reinterpret_cast<const half8*>(xh + (size_t)(ar + 16) * HID + ko);
        half8 b0 = *reinterpret_cast<const half8*>(Wp + (size_t)br * HID + ko);
        half8 b1 = *reinterpret_cast<const half8*>(Wp + (size_t)(br + 16) * HID + ko);
        acc[0][0] = __builtin_amdgcn_mfma_f32_16x16x32_f16(a0, b0, acc[0][0], 0, 0, 0);
        acc[0][1] = __builtin_amdgcn_mfma_f32_16x16x32_f16(a0, b1, acc[0][1], 0, 0, 0);
        acc[1][0] = __builtin_amdgcn_mfma_f32_16x16x32_f16(a1, b0, acc[1][0], 0, 0, 0);
        acc[1][1] = __builtin_amdgcn_mfma_f32_16x16x32_f16(a1, b1, acc[1][1], 0, 0, 0);
    }
#pragma unroll
    for (int mf = 0; mf < 2; ++mf)
#pragma unroll
    for (int nf = 0; nf < 2; ++nf)
#pragma unroll
    for (int r = 0; r < 4; ++r) {
        const int m  = m0 + wr + mf * 16 + lg * 4 + r;
        const int o  = n0 + wc + nf * 16 + lr;
        const int bb = m >> 12, nn = m & (SEQ - 1);
        const int hh = o >> 5,  dd = o & (DH - 1);
        float v = acc[mf][nf][r] + bias[o];
        if (z == 0) {
            Qh[(((size_t)(bb * NHEAD + hh) * SEQ) + nn) * DH + dd] =
                (_Float16)(v * QSCALE);
        } else if (z == 1) {
            Kh[(((size_t)(bb * NHEAD + hh) * SEQ) + nn) * DH + dd] = (_Float16)v;
        } else {
            Vt[(((size_t)(bb * NHEAD + hh) * DH) + dd) * SEQ + nn] = (_Float16)v;
        }
    }
}

// ---------------------------------------------------------------- attention
// grid (SEQ/16, BATCH), 512 threads = 8 waves = 8 heads. i-tile 16 rows.
// Swapped QK^T: S^T = mfma(K, Q) puts a full row-slice (i = lane&15) in each
// lane -> lane-local online softmax (defer-max, exp2 domain, no shuffles on
// the common path). P packed to LDS as half4 b64 writes; PV reads b128.
// Chunks of 256 keys: 3 barriers per 4 j-tiles. All blocks sweep j in the
// same order (L2-friendly, no j-split).
__global__ __launch_bounds__(512, 4) void attn_kernel(
    const _Float16* __restrict__ Qh, const _Float16* __restrict__ Kh,
    const _Float16* __restrict__ Vt, const float* __restrict__ pos,
    _Float16* __restrict__ AO)
{
    __shared__ __align__(16) float pi4[16][4];
    __shared__ __align__(16) float pj4[256][4];
    __shared__ __align__(16) float biasL[16][260];      // stride 260 dwords (%32==4, 16B-aligned rows)
    __shared__ __align__(16) _Float16 Pl[NHEAD][16 * 72]; // row stride 144B
    __shared__ __align__(16) float xposeL[NHEAD][16];

    const int b    = blockIdx.y;
    const int i0   = blockIdx.x * 16;
    const int tid  = threadIdx.x;
    const int w    = tid >> 6;           // head
    const int lane = tid & 63;
    const int lr   = lane & 15, lg = lane >> 4;

    if (tid < 16) {
        const float* p = pos + (size_t)(b * SEQ + i0 + tid) * 3;
        float x = p[0], y = p[1], z = p[2];
        pi4[tid][0] = x; pi4[tid][1] = y; pi4[tid][2] = z;
        pi4[tid][3] = x * x + y * y + z * z;
    }

    const size_t bhh = (size_t)(b * NHEAD + w);
    const _Float16* Qbase = Qh + (bhh * SEQ + i0) * DH;
    const _Float16* Kbase = Kh + bhh * SEQ * DH;
    const _Float16* Vbase = Vt + bhh * DH * SEQ;

    const half8 aq = *reinterpret_cast<const half8*>(Qbase + (size_t)lr * DH + lg * 8);

    f32x4 acc0 = {}, acc1 = {};
    float mrun = -1e30f, lsum = 0.f;

    char* PlW = (char*)&Pl[w][0];

    for (int ch = 0; ch < SEQ / 256; ++ch) {
        __syncthreads();                       // protect pj4/biasL from prev chunk readers
        if (tid < 256) {
            const float* p = pos + (size_t)(b * SEQ + ch * 256 + tid) * 3;
            float x = p[0], y = p[1], z = p[2];
            pj4[tid][0] = x; pj4[tid][1] = y; pj4[tid][2] = z;
            pj4[tid][3] = x * x + y * y + z * z;
        }
        __syncthreads();
        {   // bias tile 16 x 256: 8 values per thread, b128 stores
            const int br  = tid & 15;
            const int c0  = (tid >> 4) * 8;
            const float xi = pi4[br][0], yi = pi4[br][1], zi = pi4[br][2], si = pi4[br][3];
            f32x4 o0, o1;
#pragma unroll
            for (int k = 0; k < 8; ++k) {
                const float* pj = &pj4[c0 + k][0];
                float dot = xi * pj[0] + yi * pj[1] + zi * pj[2];
                float d2  = si + pj[3] - 2.f * dot;
                float v   = BIASC * sqrtf(fmaxf(d2, 0.f));
                if (k < 4) o0[k] = v; else o1[k - 4] = v;
            }
            *reinterpret_cast<f32x4*>(&biasL[br][c0])     = o0;
            *reinterpret_cast<f32x4*>(&biasL[br][c0 + 4]) = o1;
        }
        __syncthreads();

        for (int s = 0; s < 4; ++s) {
            const int j0 = ch * 256 + s * 64;

            // ---- S^T = K Q^T : lane holds S[i=lr][j = s*64+cf*16+lg*4+t]
            half8 k8[4];
#pragma unroll
            for (int cf = 0; cf < 4; ++cf)
                k8[cf] = *reinterpret_cast<const half8*>(
                    Kbase + (size_t)(j0 + cf * 16 + lr) * DH + lg * 8);

            f32x4 vv[4];
#pragma unroll
            for (int cf = 0; cf < 4; ++cf) {
                f32x4 zero = {};
                f32x4 sv = __builtin_amdgcn_mfma_f32_16x16x32_f16(k8[cf], aq, zero, 0, 0, 0);
                f32x4 bb = *reinterpret_cast<const f32x4*>(
                    &biasL[lr][s * 64 + cf * 16 + lg * 4]);
                vv[cf] = sv + bb;
            }

            // ---- lane-local defer-max online softmax (log2 domain)
            float tmax = vv[0][0];
#pragma unroll
            for (int cf = 0; cf < 4; ++cf)
#pragma unroll
            for (int t = 0; t < 4; ++t) tmax = fmaxf(tmax, vv[cf][t]);

            if (!__all(tmax <= mrun + THR_L2)) {     // rare rescale path
                float tm = tmax;
                tm = fmaxf(tm, __shfl_xor(tm, 16, 64));
                tm = fmaxf(tm, __shfl_xor(tm, 32, 64));
                const float mnew  = fmaxf(mrun, tm);
                const float alpha = exp2f(mrun - mnew);
                if (lane < 16) xposeL[w][lane] = alpha;
                f32x4 a4 = *reinterpret_cast<const f32x4*>(&xposeL[w][lg * 4]);
                lsum *= alpha;
                mrun = mnew;
                acc0 *= a4;
                acc1 *= a4;
            }

#pragma unroll
            for (int cf = 0; cf < 4; ++cf) {
                f32x4 p;
#pragma unroll
                for (int t = 0; t < 4; ++t) p[t] = exp2f(vv[cf][t] - mrun);
                lsum += (p[0] + p[1]) + (p[2] + p[3]);
                half4 hp;
#pragma unroll
                for (int t = 0; t < 4; ++t) hp[t] = (_Float16)p[t];
                *reinterpret_cast<half4*>(
                    PlW + lr * 144 + (cf * 16 + lg * 4) * 2) = hp;
            }

            // ---- PV: acc += P(16x64) @ V(64x32); wave-private P
#pragma unroll
            for (int ks = 0; ks < 2; ++ks) {
                half8 pa = *reinterpret_cast<const half8*>(
                    PlW + lr * 144 + (ks * 32 + lg * 8) * 2);
                half8 bv0 = *reinterpret_cast<const half8*>(
                    Vbase + (size_t)lr * SEQ + j0 + ks * 32 + lg * 8);
                half8 bv1 = *reinterpret_cast<const half8*>(
                    Vbase + (size_t)(16 + lr) * SEQ + j0 + ks * 32 + lg * 8);
                acc0 = __builtin_amdgcn_mfma_f32_16x16x32_f16(pa, bv0, acc0, 0, 0, 0);
                acc1 = __builtin_amdgcn_mfma_f32_16x16x32_f16(pa, bv1, acc1, 0, 0, 0);
            }
        }
    }

    // ---- epilogue
    lsum += __shfl_xor(lsum, 16, 64);
    lsum += __shfl_xor(lsum, 32, 64);
    const float inv = 1.f / lsum;                    // lane layout i=lr
    if (lane < 16) xposeL[w][lane] = inv;
    f32x4 i4 = *reinterpret_cast<const f32x4*>(&xposeL[w][lg * 4]);
#pragma unroll
    for (int t = 0; t < 4; ++t) {
        const size_t row = (size_t)(b * SEQ + i0 + lg * 4 + t) * HID + w * DH;
        AO[row + lr]      = (_Float16)(acc0[t] * i4[t]);
        AO[row + 16 + lr] = (_Float16)(acc1[t] * i4[t]);
    }
}

// ---------------------------------------------------------------- out proj
__global__ __launch_bounds__(256) void out_proj(
    const _Float16* __restrict__ AO, const _Float16* __restrict__ Woh,
    const float* __restrict__ bo, float* __restrict__ out)
{
    const int m0  = blockIdx.x * 64;
    const int n0  = blockIdx.y * 64;
    const int tid = threadIdx.x;
    const int w   = tid >> 6, lane = tid & 63;
    const int lr  = lane & 15, lg = lane >> 4;
    const int wr  = (w >> 1) * 32, wc = (w & 1) * 32;

    f32x4 acc[2][2] = {};
    const int ar = m0 + wr + lr;
    const int br = n0 + wc + lr;
#pragma unroll
    for (int ks = 0; ks < 8; ++ks) {
        const int ko = ks * 32 + lg * 8;
        half8 a0 = *reinterpret_cast<const half8*>(AO + (size_t)ar * HID + ko);
        half8 a1 = *reinterpret_cast<const half8*>(AO + (size_t)(ar + 16) * HID + ko);
        half8 b0 = *reinterpret_cast<const half8*>(Woh + (size_t)br * HID + ko);
        half8 b1 = *reinterpret_cast<const half8*>(Woh + (size_t)(br + 16) * HID + ko);
        acc[0][0] = __builtin_amdgcn_mfma_f32_16x16x32_f16(a0, b0, acc[0][0], 0, 0, 0);
        acc[0][1] = __builtin_amdgcn_mfma_f32_16x16x32_f16(a0, b1, acc[0][1], 0, 0, 0);
        acc[1][0] = __builtin_amdgcn_mfma_f32_16x16x32_f16(a1, b0, acc[1][0], 0, 0, 0);
        acc[1][1] = __builtin_amdgcn_mfma_f32_16x16x32_f16(a1, b1, acc[1][1], 0, 0, 0);
    }
#pragma unroll
    for (int mf = 0; mf < 2; ++mf)
#pragma unroll
    for (int nf = 0; nf < 2; ++nf)
#pragma unroll
    for (int r = 0; r < 4; ++r) {
        const int m = m0 + wr + mf * 16 + lg * 4 + r;
        const int o = n0 + wc + nf * 16 + lr;
        out[(size_t)m * HID + o] = acc[mf][nf][r] + bo[o];
    }
}

// ---------------------------------------------------------------- launch
extern "C" void kernel_launch(void* const* d_in, const int* in_sizes, int n_in,
                              void* d_out, int out_size, void* d_ws, size_t ws_size,
                              hipStream_t stream)
{
    const float* x   = (const float*)d_in[0];
    const float* pos = (const float*)d_in[1];
    const float* Wq  = (const float*)d_in[2];
    const float* bq  = (const float*)d_in[3];
    const float* Wk  = (const float*)d_in[4];
    const float* bk  = (const float*)d_in[5];
    const float* Wv  = (const float*)d_in[6];
    const float* bv  = (const float*)d_in[7];
    const float* Wo  = (const float*)d_in[8];
    const float* bo  = (const float*)d_in[9];
    float* out = (float*)d_out;

    char* ws = (char*)d_ws;
    _Float16* Qh = (_Float16*)(ws);                 // 4 MB
    _Float16* Kh = (_Float16*)(ws + (4  << 20));    // 4 MB
    _Float16* Vt = (_Float16*)(ws + (8  << 20));    // 4 MB
    _Float16* xh = (_Float16*)(ws + (12 << 20));    // 4 MB (reused as AO)
    _Float16* AO = xh;                              // safe: attn runs after qkv_proj
    _Float16* Wh = (_Float16*)(ws + (16 << 20));    // 512 KB

    const int NX = BATCH * SEQ * HID;               // 2,097,152
    const int NW = HID * HID;                       // 65,536
    cvt_f32_f16<<<NX / 1024, 256, 0, stream>>>(x, xh, NX);
    cvt_w4<<<dim3(NW / 1024, 4), 256, 0, stream>>>(Wq, Wk, Wv, Wo, Wh);

    qkv_proj<<<dim3(BATCH * SEQ / 64, HID / 64, 3), 256, 0, stream>>>(
        xh, Wh, bq, bk, bv, Qh, Kh, Vt);

    attn_kernel<<<dim3(SEQ / 16, BATCH), 512, 0, stream>>>(Qh, Kh, Vt, pos, AO);

    out_proj<<<dim3(BATCH * SEQ / 64, HID / 64), 256, 0, stream>>>(
        AO, Wh + 3 * NW, bo, out);
}

// Round 5
// 235.711 us; speedup vs baseline: 1.3874x; 1.0001x over previous
//
#include <hip/hip_runtime.h>

#define BATCH 2
#define SEQ   4096
#define HID   256
#define NHEAD 8
#define DH    32
// defer-max threshold in log2 units (≈ 8 nats)
#define THR_L2 11.5f
// 1/sqrt(32) * log2(e)
#define QSCALE 0.25501639769925074f
// -(1/10) * log2(e)
#define BIASC (-0.14426950408889634f)

typedef __attribute__((ext_vector_type(8))) _Float16 half8;
typedef __attribute__((ext_vector_type(4))) _Float16 half4;
typedef __attribute__((ext_vector_type(2))) __fp16   fp16x2;
typedef __attribute__((ext_vector_type(4))) float    f32x4;

__device__ __forceinline__ float fast_exp2(float x) {
    return __builtin_amdgcn_exp2f(x);
}

// ---------------------------------------------------------------- convert
__global__ void cvt_f32_f16(const float* __restrict__ src,
                            _Float16* __restrict__ dst, int n) {
    int i = (blockIdx.x * blockDim.x + threadIdx.x) * 4;
    if (i >= n) return;
    f32x4 v = *reinterpret_cast<const f32x4*>(src + i);
    half4 h;
#pragma unroll
    for (int c = 0; c < 4; ++c) h[c] = (_Float16)v[c];
    *reinterpret_cast<half4*>(dst + i) = h;
}

__global__ void cvt_w4(const float* __restrict__ a, const float* __restrict__ b,
                       const float* __restrict__ c, const float* __restrict__ d,
                       _Float16* __restrict__ dst) {
    const float* srcs[4] = {a, b, c, d};
    const float* s = srcs[blockIdx.y];
    const int i = (blockIdx.x * blockDim.x + threadIdx.x) * 4;
    f32x4 v = *reinterpret_cast<const f32x4*>(s + i);
    half4 h;
#pragma unroll
    for (int k = 0; k < 4; ++k) h[k] = (_Float16)v[k];
    *reinterpret_cast<half4*>(dst + (size_t)blockIdx.y * HID * HID + i) = h;
}

// ---------------------------------------------------------------- QKV proj
__global__ __launch_bounds__(256) void qkv_proj(
    const _Float16* __restrict__ xh, const _Float16* __restrict__ Wh,
    const float* __restrict__ bq, const float* __restrict__ bk,
    const float* __restrict__ bv,
    _Float16* __restrict__ Qh, _Float16* __restrict__ Kh,
    _Float16* __restrict__ Vt)
{
    const int z   = blockIdx.z;
    const int m0  = blockIdx.x * 64;
    const int n0  = blockIdx.y * 64;
    const int tid = threadIdx.x;
    const int w   = tid >> 6, lane = tid & 63;
    const int lr  = lane & 15, lg = lane >> 4;
    const int wr  = (w >> 1) * 32, wc = (w & 1) * 32;

    const _Float16* Wp = Wh + (size_t)z * HID * HID;
    const float* bias = (z == 0) ? bq : (z == 1) ? bk : bv;

    f32x4 acc[2][2] = {};
    const int ar = m0 + wr + lr;
    const int br = n0 + wc + lr;
#pragma unroll
    for (int ks = 0; ks < 8; ++ks) {
        const int ko = ks * 32 + lg * 8;
        half8 a0 = *reinterpret_cast<const half8*>(xh + (size_t)ar * HID + ko);
        half8 a1 = *reinterpret_cast<const half8*>(xh + (size_t)(ar + 16) * HID + ko);
        half8 b0 = *reinterpret_cast<const half8*>(Wp + (size_t)br * HID + ko);
        half8 b1 = *reinterpret_cast<const half8*>(Wp + (size_t)(br + 16) * HID + ko);
        acc[0][0] = __builtin_amdgcn_mfma_f32_16x16x32_f16(a0, b0, acc[0][0], 0, 0, 0);
        acc[0][1] = __builtin_amdgcn_mfma_f32_16x16x32_f16(a0, b1, acc[0][1], 0, 0, 0);
        acc[1][0] = __builtin_amdgcn_mfma_f32_16x16x32_f16(a1, b0, acc[1][0], 0, 0, 0);
        acc[1][1] = __builtin_amdgcn_mfma_f32_16x16x32_f16(a1, b1, acc[1][1], 0, 0, 0);
    }
#pragma unroll
    for (int mf = 0; mf < 2; ++mf)
#pragma unroll
    for (int nf = 0; nf < 2; ++nf)
#pragma unroll
    for (int r = 0; r < 4; ++r) {
        const int m  = m0 + wr + mf * 16 + lg * 4 + r;
        const int o  = n0 + wc + nf * 16 + lr;
        const int bb = m >> 12, nn = m & (SEQ - 1);
        const int hh = o >> 5,  dd = o & (DH - 1);
        float v = acc[mf][nf][r] + bias[o];
        if (z == 0) {
            Qh[(((size_t)(bb * NHEAD + hh) * SEQ) + nn) * DH + dd] =
                (_Float16)(v * QSCALE);
        } else if (z == 1) {
            Kh[(((size_t)(bb * NHEAD + hh) * SEQ) + nn) * DH + dd] = (_Float16)v;
        } else {
            Vt[(((size_t)(bb * NHEAD + hh) * DH) + dd) * SEQ + nn] = (_Float16)v;
        }
    }
}

// ---------------------------------------------------------------- attention
// grid (SEQ/16, BATCH), 512 threads = 8 waves = 8 heads. i-tile 16 rows.
// Swapped QK^T with bias passed as the MFMA C operand. Lane-local defer-max
// softmax in exp2 domain. P packed via cvt_pkrtz, b64 LDS writes, b128 reads.
// 512-key chunks (3 barriers per 8 j-tiles). K prefetched one tile ahead.
__global__ __launch_bounds__(512, 4) void attn_kernel(
    const _Float16* __restrict__ Qh, const _Float16* __restrict__ Kh,
    const _Float16* __restrict__ Vt, const float* __restrict__ pos,
    _Float16* __restrict__ AO)
{
    __shared__ __align__(16) float pi4[16][4];
    __shared__ __align__(16) float pj4[512][4];
    __shared__ __align__(16) float biasL[16][516];        // 33 KB
    __shared__ __align__(16) _Float16 Pl[NHEAD][16 * 72]; // 144B row stride
    __shared__ __align__(16) float xposeL[NHEAD][16];

    const int b    = blockIdx.y;
    const int i0   = blockIdx.x * 16;
    const int tid  = threadIdx.x;
    const int w    = tid >> 6;           // head
    const int lane = tid & 63;
    const int lr   = lane & 15, lg = lane >> 4;

    if (tid < 16) {
        const float* p = pos + (size_t)(b * SEQ + i0 + tid) * 3;
        float x = p[0], y = p[1], z = p[2];
        pi4[tid][0] = x; pi4[tid][1] = y; pi4[tid][2] = z;
        pi4[tid][3] = x * x + y * y + z * z;
    }

    const size_t bhh = (size_t)(b * NHEAD + w);
    const _Float16* Qbase = Qh + (bhh * SEQ + i0) * DH;
    const _Float16* Kl  = Kh + bhh * SEQ * DH + (size_t)lr * DH + lg * 8;
    const _Float16* Vl0 = Vt + bhh * DH * SEQ + (size_t)lr * SEQ + lg * 8;
    const _Float16* Vl1 = Vt + bhh * DH * SEQ + (size_t)(16 + lr) * SEQ + lg * 8;

    const half8 aq = *reinterpret_cast<const half8*>(Qbase + (size_t)lr * DH + lg * 8);

    f32x4 acc0 = {}, acc1 = {};
    float mrun = -1e30f, lsum = 0.f;

    char* PlW = (char*)&Pl[w][0];

    for (int ch = 0; ch < SEQ / 512; ++ch) {
        __syncthreads();                       // protect pj4/biasL from prev chunk readers
        {
            const float* p = pos + (size_t)(b * SEQ + ch * 512 + tid) * 3;
            float x = p[0], y = p[1], z = p[2];
            pj4[tid][0] = x; pj4[tid][1] = y; pj4[tid][2] = z;
            pj4[tid][3] = x * x + y * y + z * z;
        }
        __syncthreads();
        {   // bias tile 16 x 512: 16 values per thread, b128 stores
            const int br  = tid & 15;
            const int c0  = (tid >> 4) * 16;
            const float xi = pi4[br][0], yi = pi4[br][1], zi = pi4[br][2], si = pi4[br][3];
#pragma unroll
            for (int k4 = 0; k4 < 4; ++k4) {
                f32x4 o;
#pragma unroll
                for (int k = 0; k < 4; ++k) {
                    const float* pj = &pj4[c0 + k4 * 4 + k][0];
                    float dot = xi * pj[0] + yi * pj[1] + zi * pj[2];
                    float d2  = si + pj[3] - 2.f * dot;
                    o[k] = BIASC * sqrtf(fmaxf(d2, 0.f));
                }
                *reinterpret_cast<f32x4*>(&biasL[br][c0 + k4 * 4]) = o;
            }
        }
        __syncthreads();

        // preload K for tile s=0 of this chunk
        half8 k8[4];
#pragma unroll
        for (int cf = 0; cf < 4; ++cf)
            k8[cf] = *reinterpret_cast<const half8*>(
                Kl + (size_t)(ch * 512 + cf * 16) * DH);

#pragma unroll 2
        for (int s = 0; s < 8; ++s) {
            const int j0 = ch * 512 + s * 64;

            // V loads issue early; consumed by PV after softmax
            half8 bva = *reinterpret_cast<const half8*>(Vl0 + j0);
            half8 bvb = *reinterpret_cast<const half8*>(Vl1 + j0);
            half8 bvc = *reinterpret_cast<const half8*>(Vl0 + j0 + 32);
            half8 bvd = *reinterpret_cast<const half8*>(Vl1 + j0 + 32);

            // ---- S^T = K Q^T + bias (bias rides the C operand)
            f32x4 vv[4];
#pragma unroll
            for (int cf = 0; cf < 4; ++cf) {
                f32x4 cb = *reinterpret_cast<const f32x4*>(
                    &biasL[lr][s * 64 + cf * 16 + lg * 4]);
                vv[cf] = __builtin_amdgcn_mfma_f32_16x16x32_f16(k8[cf], aq, cb, 0, 0, 0);
            }

            // prefetch next tile's K under the softmax
            half8 kn[4];
            if (s < 7) {
#pragma unroll
                for (int cf = 0; cf < 4; ++cf)
                    kn[cf] = *reinterpret_cast<const half8*>(
                        Kl + (size_t)(j0 + 64 + cf * 16) * DH);
            }

            // ---- lane-local defer-max online softmax (log2 domain)
            float tmax = fmaxf(fmaxf(vv[0][0], vv[0][1]), vv[0][2]);
            tmax = fmaxf(fmaxf(tmax, vv[0][3]), vv[1][0]);
            tmax = fmaxf(fmaxf(tmax, vv[1][1]), vv[1][2]);
            tmax = fmaxf(fmaxf(tmax, vv[1][3]), vv[2][0]);
            tmax = fmaxf(fmaxf(tmax, vv[2][1]), vv[2][2]);
            tmax = fmaxf(fmaxf(tmax, vv[2][3]), vv[3][0]);
            tmax = fmaxf(fmaxf(tmax, vv[3][1]), vv[3][2]);
            tmax = fmaxf(tmax, vv[3][3]);

            if (!__all(tmax <= mrun + THR_L2)) {     // rare rescale path
                float tm = tmax;
                tm = fmaxf(tm, __shfl_xor(tm, 16, 64));
                tm = fmaxf(tm, __shfl_xor(tm, 32, 64));
                const float mnew  = fmaxf(mrun, tm);
                const float alpha = fast_exp2(mrun - mnew);
                if (lane < 16) xposeL[w][lane] = alpha;
                f32x4 a4 = *reinterpret_cast<const f32x4*>(&xposeL[w][lg * 4]);
                lsum *= alpha;
                mrun = mnew;
                acc0 *= a4;
                acc1 *= a4;
            }

#pragma unroll
            for (int cf = 0; cf < 4; ++cf) {
                float p0 = fast_exp2(vv[cf][0] - mrun);
                float p1 = fast_exp2(vv[cf][1] - mrun);
                float p2 = fast_exp2(vv[cf][2] - mrun);
                float p3 = fast_exp2(vv[cf][3] - mrun);
                lsum += (p0 + p1) + (p2 + p3);
                fp16x2 ha = __builtin_amdgcn_cvt_pkrtz(p0, p1);
                fp16x2 hb = __builtin_amdgcn_cvt_pkrtz(p2, p3);
                unsigned int wlo = __builtin_bit_cast(unsigned int, ha);
                unsigned int whi = __builtin_bit_cast(unsigned int, hb);
                unsigned long long wq =
                    (unsigned long long)wlo | ((unsigned long long)whi << 32);
                *reinterpret_cast<unsigned long long*>(
                    PlW + lr * 144 + (cf * 16 + lg * 4) * 2) = wq;
            }

            // ---- PV: acc += P(16x64) @ V(64x32); wave-private P
            half8 pa0 = *reinterpret_cast<const half8*>(PlW + lr * 144 + (lg * 8) * 2);
            half8 pa1 = *reinterpret_cast<const half8*>(PlW + lr * 144 + (32 + lg * 8) * 2);
            acc0 = __builtin_amdgcn_mfma_f32_16x16x32_f16(pa0, bva, acc0, 0, 0, 0);
            acc1 = __builtin_amdgcn_mfma_f32_16x16x32_f16(pa0, bvb, acc1, 0, 0, 0);
            acc0 = __builtin_amdgcn_mfma_f32_16x16x32_f16(pa1, bvc, acc0, 0, 0, 0);
            acc1 = __builtin_amdgcn_mfma_f32_16x16x32_f16(pa1, bvd, acc1, 0, 0, 0);

            if (s < 7) {
#pragma unroll
                for (int cf = 0; cf < 4; ++cf) k8[cf] = kn[cf];
            }
        }
    }

    // ---- epilogue
    lsum += __shfl_xor(lsum, 16, 64);
    lsum += __shfl_xor(lsum, 32, 64);
    const float inv = 1.f / lsum;                    // lane layout i=lr
    if (lane < 16) xposeL[w][lane] = inv;
    f32x4 i4 = *reinterpret_cast<const f32x4*>(&xposeL[w][lg * 4]);
#pragma unroll
    for (int t = 0; t < 4; ++t) {
        const size_t row = (size_t)(b * SEQ + i0 + lg * 4 + t) * HID + w * DH;
        AO[row + lr]      = (_Float16)(acc0[t] * i4[t]);
        AO[row + 16 + lr] = (_Float16)(acc1[t] * i4[t]);
    }
}

// ---------------------------------------------------------------- out proj
__global__ __launch_bounds__(256) void out_proj(
    const _Float16* __restrict__ AO, const _Float16* __restrict__ Woh,
    const float* __restrict__ bo, float* __restrict__ out)
{
    const int m0  = blockIdx.x * 64;
    const int n0  = blockIdx.y * 64;
    const int tid = threadIdx.x;
    const int w   = tid >> 6, lane = tid & 63;
    const int lr  = lane & 15, lg = lane >> 4;
    const int wr  = (w >> 1) * 32, wc = (w & 1) * 32;

    f32x4 acc[2][2] = {};
    const int ar = m0 + wr + lr;
    const int br = n0 + wc + lr;
#pragma unroll
    for (int ks = 0; ks < 8; ++ks) {
        const int ko = ks * 32 + lg * 8;
        half8 a0 = *reinterpret_cast<const half8*>(AO + (size_t)ar * HID + ko);
        half8 a1 = *reinterpret_cast<const half8*>(AO + (size_t)(ar + 16) * HID + ko);
        half8 b0 = *reinterpret_cast<const half8*>(Woh + (size_t)br * HID + ko);
        half8 b1 = *reinterpret_cast<const half8*>(Woh + (size_t)(br + 16) * HID + ko);
        acc[0][0] = __builtin_amdgcn_mfma_f32_16x16x32_f16(a0, b0, acc[0][0], 0, 0, 0);
        acc[0][1] = __builtin_amdgcn_mfma_f32_16x16x32_f16(a0, b1, acc[0][1], 0, 0, 0);
        acc[1][0] = __builtin_amdgcn_mfma_f32_16x16x32_f16(a1, b0, acc[1][0], 0, 0, 0);
        acc[1][1] = __builtin_amdgcn_mfma_f32_16x16x32_f16(a1, b1, acc[1][1], 0, 0, 0);
    }
#pragma unroll
    for (int mf = 0; mf < 2; ++mf)
#pragma unroll
    for (int nf = 0; nf < 2; ++nf)
#pragma unroll
    for (int r = 0; r < 4; ++r) {
        const int m = m0 + wr + mf * 16 + lg * 4 + r;
        const int o = n0 + wc + nf * 16 + lr;
        out[(size_t)m * HID + o] = acc[mf][nf][r] + bo[o];
    }
}

// ---------------------------------------------------------------- launch
extern "C" void kernel_launch(void* const* d_in, const int* in_sizes, int n_in,
                              void* d_out, int out_size, void* d_ws, size_t ws_size,
                              hipStream_t stream)
{
    const float* x   = (const float*)d_in[0];
    const float* pos = (const float*)d_in[1];
    const float* Wq  = (const float*)d_in[2];
    const float* bq  = (const float*)d_in[3];
    const float* Wk  = (const float*)d_in[4];
    const float* bk  = (const float*)d_in[5];
    const float* Wv  = (const float*)d_in[6];
    const float* bv  = (const float*)d_in[7];
    const float* Wo  = (const float*)d_in[8];
    const float* bo  = (const float*)d_in[9];
    float* out = (float*)d_out;

    char* ws = (char*)d_ws;
    _Float16* Qh = (_Float16*)(ws);                 // 4 MB
    _Float16* Kh = (_Float16*)(ws + (4  << 20));    // 4 MB
    _Float16* Vt = (_Float16*)(ws + (8  << 20));    // 4 MB
    _Float16* xh = (_Float16*)(ws + (12 << 20));    // 4 MB (reused as AO)
    _Float16* AO = xh;                              // safe: attn runs after qkv_proj
    _Float16* Wh = (_Float16*)(ws + (16 << 20));    // 512 KB

    const int NX = BATCH * SEQ * HID;               // 2,097,152
    const int NW = HID * HID;                       // 65,536
    cvt_f32_f16<<<NX / 1024, 256, 0, stream>>>(x, xh, NX);
    cvt_w4<<<dim3(NW / 1024, 4), 256, 0, stream>>>(Wq, Wk, Wv, Wo, Wh);

    qkv_proj<<<dim3(BATCH * SEQ / 64, HID / 64, 3), 256, 0, stream>>>(
        xh, Wh, bq, bk, bv, Qh, Kh, Vt);

    attn_kernel<<<dim3(SEQ / 16, BATCH), 512, 0, stream>>>(Qh, Kh, Vt, pos, AO);

    out_proj<<<dim3(BATCH * SEQ / 64, HID / 64), 256, 0, stream>>>(
        AO, Wh + 3 * NW, bo, out);
}